// Round 5
// baseline (389.550 us; speedup 1.0000x reference)
//
#include <hip/hip_runtime.h>
#include <stdint.h>

typedef __bf16  bf16x8  __attribute__((ext_vector_type(8)));
typedef float   f32x4   __attribute__((ext_vector_type(4)));
typedef unsigned short ushort8 __attribute__((ext_vector_type(8)));
typedef unsigned short ushort4v __attribute__((ext_vector_type(4)));

#define DEV __device__ __forceinline__

DEV unsigned short f2bf(float f) {
    union { float f; unsigned u; } v; v.f = f;
    unsigned u = v.u;
    return (unsigned short)((u + 0x7FFFu + ((u >> 16) & 1u)) >> 16);
}
DEV float bf2f(unsigned short h) {
    union { unsigned u; float f; } v; v.u = ((unsigned)h) << 16;
    return v.f;
}

DEV void gload16(const void* g, void* l) {
    __builtin_amdgcn_global_load_lds(
        (const __attribute__((address_space(1))) unsigned int*)g,
        (__attribute__((address_space(3))) unsigned int*)l, 16, 0, 0);
}

// ===========================================================================
// 256x256 tile, BK=64, 8 waves (2Mx4N), double-buffered LDS (128 KiB),
// counted-vmcnt pipeline, XOR-swizzled LDS, A[M][K] * B[N][K]^T.
// Per K-tile, 4 phases, 16 MFMA each (ks-OUTER: dep distance 8):
//   P1: ds_read a0(m0-3),b01 | stage B0(t+1)->buf^1 | bar | MFMA a0*b01 | bar
//   P2: ds_read b23          | stage B1(t+1)->buf^1 | bar | MFMA a0*b23 | bar
//   P3: ds_read a1(m4-7)     | stage A0(t+2)->buf   | bar | MFMA a1*b01 | bar
//   P4:                        stage A1(t+2)->buf         | MFMA a1*b23 | vmcnt(4) | bar
// Cross-wave safety: reads of a region are consumed >=1 barrier before the
// staging that overwrites it (a0: P1-bar vs P3-stage; a1: P3-bar vs P4-stage;
// B(buf): P2-bar of iter t vs P1-stage of iter t+1). No lgkmcnt(0) drains.
// ===========================================================================
template<bool OUT_BF16>
__global__ __launch_bounds__(512, 2)
void gemm256(const unsigned short* __restrict__ A, long lda, long sA,
             const unsigned short* __restrict__ B, long ldb, long sB,
             void* __restrict__ Cv, long ldc, long sC,
             int N, int K, float alpha)
{
    __shared__ __attribute__((aligned(16))) char sm[131072];

    const int bz = blockIdx.z;
    A += (long)bz * sA;
    B += (long)bz * sB;

    const int tiles_n = N >> 8;
    int bid = blockIdx.x;
    const int nwg = gridDim.x;
    {   // bijective XCD swizzle (m204)
        const int q = nwg >> 3, r = nwg & 7;
        const int xcd = bid & 7, idx = bid >> 3;
        bid = (xcd < r ? xcd * (q + 1) : r * (q + 1) + (xcd - r) * q) + idx;
    }
    const long brow = (long)(bid / tiles_n) << 8;
    const long bcol = (long)(bid % tiles_n) << 8;

    const int t = threadIdx.x;
    const int w = t >> 6, lane = t & 63;
    const int wr = w >> 2, wc = w & 3;
    const int lr = lane & 15, lk = lane >> 4;

    // ---- staging geometry (pre-swizzled global source, linear LDS dest) ----
    const int srow = (w << 3) + (lane >> 3);                 // 0..63
    const int scol = ((lane & 7) ^ (lane >> 3)) << 3;        // swizzled col (elems)
    const unsigned short* gA = A + (brow + srow) * lda + scol;
    const unsigned short* gB = B + (bcol + srow) * ldb + scol;
    char* const dstA = sm + w * 1024;                        // +buf*65536 +half*16384 (+8192)
    char* const dstB = sm + 32768 + w * 1024;
    const long lda64 = 64 * lda, ldaH = 128 * lda;
    const long ldb64 = 64 * ldb, ldbH = 128 * ldb;

    // ---- reader geometry (XOR swizzle on colbyte: ^ (row&7)<<4) ----
    const int rsw0 = ((lk ^ (lr & 7)) << 4);                 // ks=0 colbyte; ks=1 -> ^64
    const int aoff = wr * 16384 + lr * 128;
    const int boff = 32768 + (wc >> 1) * 16384 + (((wc & 1) << 6) + lr) * 128;

    f32x4 acc[8][4];
#pragma unroll
    for (int m = 0; m < 8; ++m)
#pragma unroll
        for (int n = 0; n < 4; ++n) acc[m][n] = 0.f;

    const int nk = K >> 6;

    // ---- prologue: tile0 (4 halves) -> buf0, A-halves of tile1 -> buf1 ----
    gload16(gA,                dstA);
    gload16(gA + lda64,        dstA + 8192);
    gload16(gA + ldaH,         dstA + 16384);
    gload16(gA + ldaH + lda64, dstA + 16384 + 8192);
    gload16(gB,                dstB);
    gload16(gB + ldb64,        dstB + 8192);
    gload16(gB + ldbH,         dstB + 16384);
    gload16(gB + ldbH + ldb64, dstB + 16384 + 8192);
    if (nk > 1) {
        gload16(gA + 64,                dstA + 65536);
        gload16(gA + 64 + lda64,        dstA + 65536 + 8192);
        gload16(gA + 64 + ldaH,         dstA + 65536 + 16384);
        gload16(gA + 64 + ldaH + lda64, dstA + 65536 + 16384 + 8192);
        asm volatile("s_waitcnt vmcnt(4)" ::: "memory");
    } else {
        asm volatile("s_waitcnt vmcnt(0)" ::: "memory");
    }
    __builtin_amdgcn_s_barrier();

    const unsigned short* gAk = gA;   // bumped by +64 elems per K-tile
    const unsigned short* gBk = gB;

    for (int kt = 0; kt < nk; ++kt) {
        const int buf = kt & 1;
        const char* sa = sm + buf * 65536 + aoff;
        const char* sb = sm + buf * 65536 + boff;
        char* const dA = dstA + buf * 65536;            // A of CURRENT buf (tile kt+2)
        char* const dB = dstB + (buf ^ 1) * 65536;      // B of OTHER buf  (tile kt+1)
        bf16x8 a0[4][2], a1[4][2], b01[2][2], b23[2][2];

        // ---------------- P1: read a0,b01; stage B0(t+1) ----------------
#pragma unroll
        for (int m = 0; m < 4; ++m) {
            a0[m][0] = *(const bf16x8*)(sa + m * 2048 + rsw0);
            a0[m][1] = *(const bf16x8*)(sa + m * 2048 + (rsw0 ^ 64));
        }
#pragma unroll
        for (int n = 0; n < 2; ++n) {
            b01[n][0] = *(const bf16x8*)(sb + n * 2048 + rsw0);
            b01[n][1] = *(const bf16x8*)(sb + n * 2048 + (rsw0 ^ 64));
        }
        if (kt + 1 < nk) {
            gload16(gBk + 64,         dB);
            gload16(gBk + 64 + ldb64, dB + 8192);
        }
        __builtin_amdgcn_s_barrier();
        __builtin_amdgcn_s_setprio(1);
#pragma unroll
        for (int ks = 0; ks < 2; ++ks)
#pragma unroll
            for (int m = 0; m < 4; ++m)
#pragma unroll
                for (int n = 0; n < 2; ++n)
                    acc[m][n] = __builtin_amdgcn_mfma_f32_16x16x32_bf16(
                        a0[m][ks], b01[n][ks], acc[m][n], 0, 0, 0);
        __builtin_amdgcn_s_setprio(0);
        __builtin_amdgcn_s_barrier();

        // ---------------- P2: read b23; stage B1(t+1) ----------------
#pragma unroll
        for (int n = 0; n < 2; ++n) {
            b23[n][0] = *(const bf16x8*)(sb + (n + 2) * 2048 + rsw0);
            b23[n][1] = *(const bf16x8*)(sb + (n + 2) * 2048 + (rsw0 ^ 64));
        }
        if (kt + 1 < nk) {
            gload16(gBk + 64 + ldbH,         dB + 16384);
            gload16(gBk + 64 + ldbH + ldb64, dB + 16384 + 8192);
        }
        __builtin_amdgcn_s_barrier();
        __builtin_amdgcn_s_setprio(1);
#pragma unroll
        for (int ks = 0; ks < 2; ++ks)
#pragma unroll
            for (int m = 0; m < 4; ++m)
#pragma unroll
                for (int n = 0; n < 2; ++n)
                    acc[m][n + 2] = __builtin_amdgcn_mfma_f32_16x16x32_bf16(
                        a0[m][ks], b23[n][ks], acc[m][n + 2], 0, 0, 0);
        __builtin_amdgcn_s_setprio(0);
        __builtin_amdgcn_s_barrier();

        // ---------------- P3: read a1; stage A0(t+2) ----------------
#pragma unroll
        for (int m = 0; m < 4; ++m) {
            a1[m][0] = *(const bf16x8*)(sa + (m + 4) * 2048 + rsw0);
            a1[m][1] = *(const bf16x8*)(sa + (m + 4) * 2048 + (rsw0 ^ 64));
        }
        if (kt + 2 < nk) {
            gload16(gAk + 128,         dA);
            gload16(gAk + 128 + lda64, dA + 8192);
        }
        __builtin_amdgcn_s_barrier();
        __builtin_amdgcn_s_setprio(1);
#pragma unroll
        for (int ks = 0; ks < 2; ++ks)
#pragma unroll
            for (int m = 0; m < 4; ++m)
#pragma unroll
                for (int n = 0; n < 2; ++n)
                    acc[m + 4][n] = __builtin_amdgcn_mfma_f32_16x16x32_bf16(
                        a1[m][ks], b01[n][ks], acc[m + 4][n], 0, 0, 0);
        __builtin_amdgcn_s_setprio(0);
        __builtin_amdgcn_s_barrier();

        // ---------------- P4: stage A1(t+2); MFMA; vmcnt ----------------
        if (kt + 2 < nk) {
            gload16(gAk + 128 + ldaH,         dA + 16384);
            gload16(gAk + 128 + ldaH + lda64, dA + 16384 + 8192);
        }
        __builtin_amdgcn_s_setprio(1);
#pragma unroll
        for (int ks = 0; ks < 2; ++ks)
#pragma unroll
            for (int m = 0; m < 4; ++m)
#pragma unroll
                for (int n = 0; n < 2; ++n)
                    acc[m + 4][n + 2] = __builtin_amdgcn_mfma_f32_16x16x32_bf16(
                        a1[m][ks], b23[n][ks], acc[m + 4][n + 2], 0, 0, 0);
        __builtin_amdgcn_s_setprio(0);
        if (kt + 2 < nk) {
            asm volatile("s_waitcnt vmcnt(4)" ::: "memory");
        } else if (kt + 1 < nk) {
            asm volatile("s_waitcnt vmcnt(0)" ::: "memory");
        }
        __builtin_amdgcn_s_barrier();

        gAk += 64; gBk += 64;
    }

    // ---- epilogue: C/D layout col = lane&15, row = (lane>>4)*4 + j ----
    const long r0 = brow + wr * 128;
    const long c0 = bcol + wc * 64;
    if (OUT_BF16) {
        unsigned short* C = (unsigned short*)Cv + (long)bz * sC;
#pragma unroll
        for (int m = 0; m < 8; ++m)
#pragma unroll
            for (int n = 0; n < 4; ++n) {
                const long c = c0 + n * 16 + lr;
#pragma unroll
                for (int j = 0; j < 4; ++j) {
                    const long r = r0 + m * 16 + lk * 4 + j;
                    C[r * ldc + c] = f2bf(acc[m][n][j] * alpha);
                }
            }
    } else {
        float* C = (float*)Cv + (long)bz * sC;
#pragma unroll
        for (int m = 0; m < 8; ++m)
#pragma unroll
            for (int n = 0; n < 4; ++n) {
                const long c = c0 + n * 16 + lr;
#pragma unroll
                for (int j = 0; j < 4; ++j) {
                    const long r = r0 + m * 16 + lk * 4 + j;
                    C[r * ldc + c] = acc[m][n][j] * alpha;
                }
            }
    }
}

// ---------------------------------------------------------------------------
// fp32 -> bf16 elementwise (vectorized), grid-stride
// ---------------------------------------------------------------------------
__global__ __launch_bounds__(256)
void conv_x(const f32x4* __restrict__ X, ushort4v* __restrict__ Y, long n4)
{
    long i = (long)blockIdx.x * 256 + threadIdx.x;
    const long stride = (long)gridDim.x * 256;
    for (; i < n4; i += stride) {
        f32x4 v = X[i];
        ushort4v o;
#pragma unroll
        for (int j = 0; j < 4; ++j) o[j] = f2bf(v[j]);
        Y[i] = o;
    }
}

// ---------------------------------------------------------------------------
// W [3][1024][1024] fp32 -> Wt [3][1024][1024] bf16 transposed per head
// ---------------------------------------------------------------------------
__global__ __launch_bounds__(256)
void conv_w(const float* __restrict__ W, unsigned short* __restrict__ Wt)
{
    __shared__ unsigned short tile[64][65];
    const long hofs = (long)blockIdx.z * 1048576;
    const int d0 = blockIdx.x * 64;
    const int o0 = blockIdx.y * 64;
    const int t = threadIdx.x;
    const int c  = t & 63;
    const int r0 = t >> 6;
#pragma unroll
    for (int rr = 0; rr < 64; rr += 4) {
        const int r = rr + r0;
        tile[r][c] = f2bf(W[hofs + (long)(d0 + r) * 1024 + (o0 + c)]);
    }
    __syncthreads();
#pragma unroll
    for (int rr = 0; rr < 64; rr += 4) {
        const int r = rr + r0;
        Wt[hofs + (long)(o0 + r) * 1024 + (d0 + c)] = tile[c][r];
    }
}

// ---------------------------------------------------------------------------
// row softmax in place on bf16 [nrows][2048]; 8 rows per block
// ---------------------------------------------------------------------------
__global__ __launch_bounds__(256)
void softmax_rows(unsigned short* __restrict__ P)
{
    __shared__ float red[4];
    const int t = threadIdx.x;
    const int lane = t & 63, wave = t >> 6;

    for (int r = 0; r < 8; ++r) {
        unsigned short* p = P + ((long)blockIdx.x * 8 + r) * 2048;
        ushort8 u = *(const ushort8*)(p + t * 8);
        float x[8];
        float mx = -3.0e38f;
#pragma unroll
        for (int j = 0; j < 8; ++j) { x[j] = bf2f(u[j]); mx = fmaxf(mx, x[j]); }
#pragma unroll
        for (int o = 1; o < 64; o <<= 1) mx = fmaxf(mx, __shfl_xor(mx, o));
        if (lane == 0) red[wave] = mx;
        __syncthreads();
        mx = fmaxf(fmaxf(red[0], red[1]), fmaxf(red[2], red[3]));
        __syncthreads();

        float e[8], s = 0.f;
#pragma unroll
        for (int j = 0; j < 8; ++j) { e[j] = __expf(x[j] - mx); s += e[j]; }
#pragma unroll
        for (int o = 1; o < 64; o <<= 1) s += __shfl_xor(s, o);
        if (lane == 0) red[wave] = s;
        __syncthreads();
        s = red[0] + red[1] + red[2] + red[3];
        __syncthreads();   // red reused next row

        const float inv = 1.0f / s;
        ushort8 o8;
#pragma unroll
        for (int j = 0; j < 8; ++j) o8[j] = f2bf(e[j] * inv);
        *(ushort8*)(p + t * 8) = o8;
    }
}

// ---------------------------------------------------------------------------
extern "C" void kernel_launch(void* const* d_in, const int* in_sizes, int n_in,
                              void* d_out, int out_size, void* d_ws, size_t ws_size,
                              hipStream_t stream)
{
    const float* x = (const float*)d_in[0];   // [8,2048,1024]
    const float* w = (const float*)d_in[1];   // [3,1024,1024]
    float* out = (float*)d_out;               // [8,2048,1024] fp32

    const long BS = 16384;   // 8*2048 flattened rows
    const long D  = 1024;
    const long S  = 2048;

    char* ws = (char*)d_ws;
    unsigned short* Xb = (unsigned short*)ws; ws += BS * D * 2;            // 32 MB
    unsigned short* Wt = (unsigned short*)ws; ws += 3L * D * D * 2;        // 6 MB
    unsigned short* QK = (unsigned short*)ws; ws += BS * 2 * D * 2;        // 64 MB
    unsigned short* Vt = (unsigned short*)ws; ws += D * BS * 2;            // 32 MB
    unsigned short* P  = (unsigned short*)ws; ws += 8L * S * S * 2;        // 64 MB

    // 1) x -> bf16
    conv_x<<<4096, 256, 0, stream>>>((const f32x4*)x, (ushort4v*)Xb, BS * D / 4);
    // 2) W -> bf16, transposed per head
    conv_w<<<dim3(16, 16, 3), 256, 0, stream>>>(w, Wt);

    // 3) QK = Xb * [W0|W1]^T -> [16384][2048] bf16 (cols 0..1023=Q, 1024..2047=K)
    gemm256<true><<<dim3((BS / 256) * (2048 / 256), 1, 1), 512, 0, stream>>>(
        Xb, D, 0, Wt, D, 0, QK, 2 * D, 0, 2048, (int)D, 1.f);

    // 4) Vt[o][bs] = sum_d W2t[o][d] * Xb[bs][d] -> [1024][16384] bf16
    gemm256<true><<<dim3((1024 / 256) * (BS / 256), 1, 1), 512, 0, stream>>>(
        Wt + 2L * D * D, D, 0, Xb, D, 0, Vt, BS, 0, (int)BS, (int)D, 1.f);

    // 5) scores_b = Q_b * K_b^T / sqrt(2048) -> P bf16   (batched z=8)
    gemm256<true><<<dim3((S / 256) * (S / 256), 1, 8), 512, 0, stream>>>(
        QK, 2 * D, S * 2 * D,
        QK + D, 2 * D, S * 2 * D,
        P, S, S * S,
        (int)S, (int)D, 0.022097086912079612f);

    // 6) softmax rows in place
    softmax_rows<<<2048, 256, 0, stream>>>(P);

    // 7) out_b = P_b * Vt_b^T (fp32 out)   (batched z=8)
    gemm256<false><<<dim3((S / 256) * (1024 / 256), 1, 8), 512, 0, stream>>>(
        P, S, S * S,
        Vt, BS, S,
        out, D, S * D,
        1024, (int)S, 1.f);
}